// Round 4
// baseline (801.420 us; speedup 1.0000x reference)
//
#include <hip/hip_runtime.h>
#include <math.h>

// ---------------- graph build ----------------

__global__ void count_kernel(const int* __restrict__ ei, int* __restrict__ cnt, int E) {
  int e = blockIdx.x * 256 + threadIdx.x;
  if (e < E) atomicAdd(&cnt[ei[E + e]], 1);
}

__global__ void scan_block_kernel(const int* __restrict__ cnt, int* __restrict__ part,
                                  int* __restrict__ bsums, float* __restrict__ dis, int n) {
  __shared__ int wsum[4];
  int tid = threadIdx.x;
  int lane = tid & 63, wid = tid >> 6;
  int base = blockIdx.x * 1024 + tid * 4;
  int v0 = 0, v1 = 0, v2 = 0, v3 = 0;
  if (base + 0 < n) { v0 = cnt[base + 0]; dis[base + 0] = 1.f / sqrtf((float)(v0 + 1)); }
  if (base + 1 < n) { v1 = cnt[base + 1]; dis[base + 1] = 1.f / sqrtf((float)(v1 + 1)); }
  if (base + 2 < n) { v2 = cnt[base + 2]; dis[base + 2] = 1.f / sqrtf((float)(v2 + 1)); }
  if (base + 3 < n) { v3 = cnt[base + 3]; dis[base + 3] = 1.f / sqrtf((float)(v3 + 1)); }
  int tot = v0 + v1 + v2 + v3;
  int x = tot;
#pragma unroll
  for (int d = 1; d < 64; d <<= 1) { int y = __shfl_up(x, d, 64); if (lane >= d) x += y; }
  if (lane == 63) wsum[wid] = x;
  __syncthreads();
  int wpre = 0;
#pragma unroll
  for (int w = 0; w < 4; ++w) wpre += (w < wid) ? wsum[w] : 0;
  int ex = wpre + x - tot;
  if (base + 0 < n) part[base + 0] = ex; ex += v0;
  if (base + 1 < n) part[base + 1] = ex; ex += v1;
  if (base + 2 < n) part[base + 2] = ex; ex += v2;
  if (base + 3 < n) part[base + 3] = ex;
  if (tid == 255) bsums[blockIdx.x] = wpre + x;
}

// single-wave scan over block sums (nb <= a few hundred)
__global__ void scan_tops_kernel(int* __restrict__ bsums, int nb, int* __restrict__ offs, int n) {
  int lane = threadIdx.x;  // launched with 64
  int run = 0;
  for (int base = 0; base < nb; base += 64) {
    int i = base + lane;
    int v = (i < nb) ? bsums[i] : 0;
    int x = v;
#pragma unroll
    for (int d = 1; d < 64; d <<= 1) { int y = __shfl_up(x, d, 64); if (lane >= d) x += y; }
    if (i < nb) bsums[i] = run + x - v;  // exclusive prefix
    run += __shfl(x, 63, 64);
  }
  if (lane == 0) offs[n] = run;
}

__global__ void scan_add_kernel(const int* __restrict__ bsums, int* __restrict__ offs,
                                int* __restrict__ cursor, int n) {
  int i = blockIdx.x * 256 + threadIdx.x;
  if (i < n) {
    int o = offs[i] + bsums[i >> 10];
    offs[i] = o;
    cursor[i] = o;
  }
}

__global__ void fill_kernel(const int* __restrict__ ei, int* __restrict__ cursor,
                            int* __restrict__ csr, int E) {
  int e = blockIdx.x * 256 + threadIdx.x;
  if (e < E) {
    int s = ei[e];
    int d = ei[E + e];
    int pos = atomicAdd(&cursor[d], 1);
    csr[pos] = s;
  }
}

// ---------------- fp32 GEMM: C[M,NCOL] = A[M,128] @ W[128,NCOL] (+bias, relu) ----------------
// 256 threads, 128x128 row tile, 8x8 (or 8x4) micro-tile.
// Both operands k-fastest in LDS, XOR-swizzled (k4 ^= (row>>3)&7) so all
// ds_read_b128 in the k-loop are bank-conflict-free.

template <int NCOL, bool RELU, bool BIAS>
__global__ __launch_bounds__(256) void gemm_kernel(const float* __restrict__ A,
                                                   const float* __restrict__ W,
                                                   const float* __restrict__ bias,
                                                   float* __restrict__ C, int M) {
  constexpr int TN = NCOL / 16;  // 8 for 128, 4 for 64
  __shared__ float As[128 * 128];
  __shared__ float Wt[NCOL * 128];
  int tid = threadIdx.x;
  int row0 = blockIdx.x * 128;

  // stage A [128 rows x 128 k], swizzled
#pragma unroll
  for (int i = 0; i < 16; ++i) {
    int idx = tid + i * 256;       // float4 slot over 128x32
    int r = idx >> 5;
    int c4 = idx & 31;
    int gr = row0 + r;
    float4 v = make_float4(0.f, 0.f, 0.f, 0.f);
    if (gr < M) v = *reinterpret_cast<const float4*>(A + (size_t)gr * 128 + c4 * 4);
    *reinterpret_cast<float4*>(&As[r * 128 + ((c4 ^ ((r >> 3) & 7)) << 2)]) = v;
  }
  // stage W transposed -> Wt[col][k], swizzled
  constexpr int WI = (128 * (NCOL / 4)) / 256;
#pragma unroll
  for (int i = 0; i < WI; ++i) {
    int idx = tid + i * 256;
    int k = idx / (NCOL / 4);
    int c0 = (idx % (NCOL / 4)) * 4;
    float4 v = *reinterpret_cast<const float4*>(W + k * NCOL + c0);
    int k4 = k >> 2, kk = k & 3;
    Wt[(c0 + 0) * 128 + ((k4 ^ (((c0 + 0) >> 3) & 7)) << 2) + kk] = v.x;
    Wt[(c0 + 1) * 128 + ((k4 ^ (((c0 + 1) >> 3) & 7)) << 2) + kk] = v.y;
    Wt[(c0 + 2) * 128 + ((k4 ^ (((c0 + 2) >> 3) & 7)) << 2) + kk] = v.z;
    Wt[(c0 + 3) * 128 + ((k4 ^ (((c0 + 3) >> 3) & 7)) << 2) + kk] = v.w;
  }
  __syncthreads();

  int tx = tid & 15, ty = tid >> 4;
  int r0 = ty * 8;
  int cbase = tx * TN;
  int sa = ty & 7;                 // (row>>3)&7 for this thread's 8 rows
  int sw = (cbase >> 3) & 7;       // (col>>3)&7, uniform over this thread's cols

  float acc[8][TN];
#pragma unroll
  for (int r = 0; r < 8; ++r)
#pragma unroll
    for (int c = 0; c < TN; ++c) acc[r][c] = 0.f;

  for (int k4 = 0; k4 < 32; ++k4) {
    float a[8][4], w[TN][4];
    int ao = (k4 ^ sa) << 2;
    int wo = (k4 ^ sw) << 2;
#pragma unroll
    for (int r = 0; r < 8; ++r) {
      float4 v = *reinterpret_cast<const float4*>(&As[(r0 + r) * 128 + ao]);
      a[r][0] = v.x; a[r][1] = v.y; a[r][2] = v.z; a[r][3] = v.w;
    }
#pragma unroll
    for (int c = 0; c < TN; ++c) {
      float4 v = *reinterpret_cast<const float4*>(&Wt[(cbase + c) * 128 + wo]);
      w[c][0] = v.x; w[c][1] = v.y; w[c][2] = v.z; w[c][3] = v.w;
    }
#pragma unroll
    for (int kk = 0; kk < 4; ++kk)
#pragma unroll
      for (int r = 0; r < 8; ++r)
#pragma unroll
        for (int c = 0; c < TN; ++c)
          acc[r][c] = fmaf(a[r][kk], w[c][kk], acc[r][c]);
  }

#pragma unroll
  for (int r = 0; r < 8; ++r) {
    int gr = row0 + r0 + r;
    if (gr < M) {
#pragma unroll
      for (int c = 0; c < TN; c += 4) {
        float4 o;
        float v0 = acc[r][c + 0], v1 = acc[r][c + 1], v2 = acc[r][c + 2], v3 = acc[r][c + 3];
        if (BIAS) {
          v0 += bias[cbase + c + 0]; v1 += bias[cbase + c + 1];
          v2 += bias[cbase + c + 2]; v3 += bias[cbase + c + 3];
        }
        if (RELU) {
          v0 = fmaxf(v0, 0.f); v1 = fmaxf(v1, 0.f);
          v2 = fmaxf(v2, 0.f); v3 = fmaxf(v3, 0.f);
        }
        o.x = v0; o.y = v1; o.z = v2; o.w = v3;
        *reinterpret_cast<float4*>(C + (size_t)gr * NCOL + cbase + c) = o;
      }
    }
  }
}

// ---------------- pull-style aggregation ----------------
// 1 node per wave. Lanes cover features with float4; wave processes 2 (128f)
// or 4 (64f) edges per iteration, cross-slot shfl_xor reduction at the end.

__global__ __launch_bounds__(256) void agg1_kernel(const float* __restrict__ h,
                                                   const int* __restrict__ offs,
                                                   const int* __restrict__ csr,
                                                   const float* __restrict__ dis,
                                                   const float* __restrict__ b,
                                                   float* __restrict__ zout, int n) {
  int wid = threadIdx.x >> 6, lane = threadIdx.x & 63;
  int node = blockIdx.x * 4 + wid;
  if (node >= n) return;
  int half = lane >> 5;
  int fl = (lane & 31) << 2;
  float dn = dis[node];
  float4 acc = make_float4(0.f, 0.f, 0.f, 0.f);
  if (half == 0) {
    float4 hv = *reinterpret_cast<const float4*>(h + (size_t)node * 128 + fl);
    float s2 = dn * dn;
    acc.x = hv.x * s2; acc.y = hv.y * s2; acc.z = hv.z * s2; acc.w = hv.w * s2;
  }
  int jb = offs[node], je = offs[node + 1];
  for (int bs = jb; bs < je; bs += 64) {
    int idx = bs + lane;
    int sl = 0; float wl = 0.f;
    if (idx < je) { sl = csr[idx]; wl = dis[sl] * dn; }
    int m = je - bs; if (m > 64) m = 64;
    for (int t = 0; t < m; t += 4) {
      int e0 = t + half, e1 = t + 2 + half;
      int s0 = __shfl(sl, e0, 64); float w0 = __shfl(wl, e0, 64);
      int s1 = __shfl(sl, e1, 64); float w1 = __shfl(wl, e1, 64);
      float4 v0 = *reinterpret_cast<const float4*>(h + (size_t)s0 * 128 + fl);
      float4 v1 = *reinterpret_cast<const float4*>(h + (size_t)s1 * 128 + fl);
      acc.x = fmaf(v0.x, w0, acc.x); acc.y = fmaf(v0.y, w0, acc.y);
      acc.z = fmaf(v0.z, w0, acc.z); acc.w = fmaf(v0.w, w0, acc.w);
      acc.x = fmaf(v1.x, w1, acc.x); acc.y = fmaf(v1.y, w1, acc.y);
      acc.z = fmaf(v1.z, w1, acc.z); acc.w = fmaf(v1.w, w1, acc.w);
    }
  }
  acc.x += __shfl_xor(acc.x, 32, 64);
  acc.y += __shfl_xor(acc.y, 32, 64);
  acc.z += __shfl_xor(acc.z, 32, 64);
  acc.w += __shfl_xor(acc.w, 32, 64);
  if (lane < 32) {
    float4 bb = *reinterpret_cast<const float4*>(b + fl);
    float4 o;
    o.x = fmaxf(acc.x + bb.x, 0.f);
    o.y = fmaxf(acc.y + bb.y, 0.f);
    o.z = fmaxf(acc.z + bb.z, 0.f);
    o.w = fmaxf(acc.w + bb.w, 0.f);
    *reinterpret_cast<float4*>(zout + (size_t)node * 128 + fl) = o;
  }
}

__global__ __launch_bounds__(256) void agg2_kernel(const float* __restrict__ h,
                                                   const int* __restrict__ offs,
                                                   const int* __restrict__ csr,
                                                   const float* __restrict__ dis,
                                                   const float* __restrict__ b,
                                                   const float* __restrict__ zmlp,
                                                   const float* __restrict__ spi,
                                                   const float* __restrict__ logT,
                                                   float* __restrict__ out, int n) {
  int wid = threadIdx.x >> 6, lane = threadIdx.x & 63;
  int node = blockIdx.x * 4 + wid;
  if (node >= n) return;
  int slot = lane >> 4;
  int fl = (lane & 15) << 2;
  float dn = dis[node];
  float4 acc = make_float4(0.f, 0.f, 0.f, 0.f);
  if (slot == 0) {
    float4 hv = *reinterpret_cast<const float4*>(h + (size_t)node * 64 + fl);
    float s2 = dn * dn;
    acc.x = hv.x * s2; acc.y = hv.y * s2; acc.z = hv.z * s2; acc.w = hv.w * s2;
  }
  int jb = offs[node], je = offs[node + 1];
  for (int bs = jb; bs < je; bs += 64) {
    int idx = bs + lane;
    int sl = 0; float wl = 0.f;
    if (idx < je) { sl = csr[idx]; wl = dis[sl] * dn; }
    int m = je - bs; if (m > 64) m = 64;
    for (int t = 0; t < m; t += 8) {
      int e0 = t + slot, e1 = t + 4 + slot;
      int s0 = __shfl(sl, e0, 64); float w0 = __shfl(wl, e0, 64);
      int s1 = __shfl(sl, e1, 64); float w1 = __shfl(wl, e1, 64);
      float4 v0 = *reinterpret_cast<const float4*>(h + (size_t)s0 * 64 + fl);
      float4 v1 = *reinterpret_cast<const float4*>(h + (size_t)s1 * 64 + fl);
      acc.x = fmaf(v0.x, w0, acc.x); acc.y = fmaf(v0.y, w0, acc.y);
      acc.z = fmaf(v0.z, w0, acc.z); acc.w = fmaf(v0.w, w0, acc.w);
      acc.x = fmaf(v1.x, w1, acc.x); acc.y = fmaf(v1.y, w1, acc.y);
      acc.z = fmaf(v1.z, w1, acc.z); acc.w = fmaf(v1.w, w1, acc.w);
    }
  }
  acc.x += __shfl_xor(acc.x, 16, 64);
  acc.y += __shfl_xor(acc.y, 16, 64);
  acc.z += __shfl_xor(acc.z, 16, 64);
  acc.w += __shfl_xor(acc.w, 16, 64);
  acc.x += __shfl_xor(acc.x, 32, 64);
  acc.y += __shfl_xor(acc.y, 32, 64);
  acc.z += __shfl_xor(acc.z, 32, 64);
  acc.w += __shfl_xor(acc.w, 32, 64);
  if (lane < 16) {
    float beta = 1.f / (1.f + expf(-((spi[0] - 0.67f) / expf(logT[0]))));
    float4 bb = *reinterpret_cast<const float4*>(b + fl);
    float4 mv = *reinterpret_cast<const float4*>(zmlp + (size_t)node * 64 + fl);
    float4 o;
    o.x = beta * (acc.x + bb.x) + (1.f - beta) * mv.x;
    o.y = beta * (acc.y + bb.y) + (1.f - beta) * mv.y;
    o.z = beta * (acc.z + bb.z) + (1.f - beta) * mv.z;
    o.w = beta * (acc.w + bb.w) + (1.f - beta) * mv.w;
    *reinterpret_cast<float4*>(out + (size_t)node * 64 + fl) = o;
  }
}

// ---------------- launcher ----------------

extern "C" void kernel_launch(void* const* d_in, const int* in_sizes, int n_in,
                              void* d_out, int out_size, void* d_ws, size_t ws_size,
                              hipStream_t stream) {
  const float* x    = (const float*)d_in[0];
  const int*   ei   = (const int*)d_in[1];
  const float* spi  = (const float*)d_in[2];
  const float* Wg1  = (const float*)d_in[3];
  const float* bg1  = (const float*)d_in[4];
  const float* Wg2  = (const float*)d_in[5];
  const float* bg2  = (const float*)d_in[6];
  const float* Wm1  = (const float*)d_in[7];
  const float* bm1  = (const float*)d_in[8];
  const float* Wm2  = (const float*)d_in[9];
  const float* bm2  = (const float*)d_in[10];
  const float* logT = (const float*)d_in[11];
  float* out = (float*)d_out;

  int n = in_sizes[0] / 128;   // 100000
  int E = in_sizes[1] / 2;     // 1600000
  int nb = (n + 1023) / 1024;

  char* p = (char*)d_ws;
  auto alloc = [&](size_t bytes) -> char* {
    char* r = p;
    p += (bytes + 255) & ~(size_t)255;
    return r;
  };
  int*   cnt    = (int*)alloc((size_t)n * 4);
  int*   offs   = (int*)alloc((size_t)(n + 1) * 4);
  int*   cursor = (int*)alloc((size_t)n * 4);
  float* dis    = (float*)alloc((size_t)n * 4);
  int*   bsums  = (int*)alloc((size_t)nb * 4);
  int*   csr    = (int*)alloc((size_t)E * 4);
  float* h1     = (float*)alloc((size_t)n * 128 * 4);  // reused as h2
  float* hm     = (float*)alloc((size_t)n * 128 * 4);
  float* z      = (float*)alloc((size_t)n * 128 * 4);  // reused as z_mlp

  hipMemsetAsync(cnt, 0, (size_t)n * 4, stream);

  int eb = (E + 255) / 256;
  count_kernel<<<eb, 256, 0, stream>>>(ei, cnt, E);
  scan_block_kernel<<<nb, 256, 0, stream>>>(cnt, offs, bsums, dis, n);
  scan_tops_kernel<<<1, 64, 0, stream>>>(bsums, nb, offs, n);
  scan_add_kernel<<<(n + 255) / 256, 256, 0, stream>>>(bsums, offs, cursor, n);
  fill_kernel<<<eb, 256, 0, stream>>>(ei, cursor, csr, E);

  int gb = (n + 127) / 128;
  gemm_kernel<128, false, false><<<gb, 256, 0, stream>>>(x, Wg1, nullptr, h1, n);
  gemm_kernel<128, true,  true ><<<gb, 256, 0, stream>>>(x, Wm1, bm1, hm, n);
  agg1_kernel<<<(n + 3) / 4, 256, 0, stream>>>(h1, offs, csr, dis, bg1, z, n);

  float* h2   = h1;  // h1 dead after agg1
  gemm_kernel<64, false, false><<<gb, 256, 0, stream>>>(z, Wg2, nullptr, h2, n);
  float* zmlp = z;   // z dead after the gemm above (stream-ordered)
  gemm_kernel<64, false, true ><<<gb, 256, 0, stream>>>(hm, Wm2, bm2, zmlp, n);

  agg2_kernel<<<(n + 3) / 4, 256, 0, stream>>>(h2, offs, csr, dis, bg2, zmlp, spi, logT, out, n);
}

// Round 7
// 607.843 us; speedup vs baseline: 1.3185x; 1.3185x over previous
//
#include <hip/hip_runtime.h>
#include <math.h>

// ---------------- graph build ----------------
// pass 1: count in-degree AND record each edge's rank within its dst bucket.
__global__ void rank_kernel(const int* __restrict__ ei, int* __restrict__ cnt,
                            int* __restrict__ rank, int E) {
  int e = blockIdx.x * 256 + threadIdx.x;
  if (e < E) rank[e] = atomicAdd(&cnt[ei[E + e]], 1);
}

__global__ void scan_block_kernel(const int* __restrict__ cnt, int* __restrict__ part,
                                  int* __restrict__ bsums, float* __restrict__ dis, int n) {
  __shared__ int wsum[4];
  int tid = threadIdx.x;
  int lane = tid & 63, wid = tid >> 6;
  int base = blockIdx.x * 1024 + tid * 4;
  int v0 = 0, v1 = 0, v2 = 0, v3 = 0;
  if (base + 0 < n) { v0 = cnt[base + 0]; dis[base + 0] = 1.f / sqrtf((float)(v0 + 1)); }
  if (base + 1 < n) { v1 = cnt[base + 1]; dis[base + 1] = 1.f / sqrtf((float)(v1 + 1)); }
  if (base + 2 < n) { v2 = cnt[base + 2]; dis[base + 2] = 1.f / sqrtf((float)(v2 + 1)); }
  if (base + 3 < n) { v3 = cnt[base + 3]; dis[base + 3] = 1.f / sqrtf((float)(v3 + 1)); }
  int tot = v0 + v1 + v2 + v3;
  int x = tot;
#pragma unroll
  for (int d = 1; d < 64; d <<= 1) { int y = __shfl_up(x, d, 64); if (lane >= d) x += y; }
  if (lane == 63) wsum[wid] = x;
  __syncthreads();
  int wpre = 0;
#pragma unroll
  for (int w = 0; w < 4; ++w) wpre += (w < wid) ? wsum[w] : 0;
  int ex = wpre + x - tot;
  if (base + 0 < n) part[base + 0] = ex; ex += v0;
  if (base + 1 < n) part[base + 1] = ex; ex += v1;
  if (base + 2 < n) part[base + 2] = ex; ex += v2;
  if (base + 3 < n) part[base + 3] = ex;
  if (tid == 255) bsums[blockIdx.x] = wpre + x;
}

__global__ void scan_tops_kernel(int* __restrict__ bsums, int nb, int* __restrict__ offs, int n) {
  int lane = threadIdx.x;  // launched with 64
  int run = 0;
  for (int base = 0; base < nb; base += 64) {
    int i = base + lane;
    int v = (i < nb) ? bsums[i] : 0;
    int x = v;
#pragma unroll
    for (int d = 1; d < 64; d <<= 1) { int y = __shfl_up(x, d, 64); if (lane >= d) x += y; }
    if (i < nb) bsums[i] = run + x - v;  // exclusive prefix
    run += __shfl(x, 63, 64);
  }
  if (lane == 0) offs[n] = run;
}

__global__ void scan_add_kernel(const int* __restrict__ bsums, int* __restrict__ offs, int n) {
  int i = blockIdx.x * 256 + threadIdx.x;
  if (i < n) offs[i] += bsums[i >> 10];
}

// pass 2: place src into CSR slot — no atomics.
__global__ void scatter_kernel(const int* __restrict__ ei, const int* __restrict__ rank,
                               const int* __restrict__ offs, int* __restrict__ csr, int E) {
  int e = blockIdx.x * 256 + threadIdx.x;
  if (e < E) {
    int s = ei[e];
    int d = ei[E + e];
    csr[offs[d] + rank[e]] = s;
  }
}

// ---------------- fp32 GEMM v2: C[M,NCOL] = A[M,128] @ W[128,NCOL] (+bias, relu) --------
// 256 threads, 128-row x NCOL tile, 8 x TN micro-tile.
// Only Wt (transposed, XOR-swizzled) lives in LDS (64/32 KB -> 2+ blocks/CU).
// A is read from global per k4-step with 16-lane broadcast transactions (each
// block touches its A tile exactly once); explicit ping-pong register prefetch,
// no barrier in the k-loop.

template <int NCOL, bool RELU, bool BIAS>
__global__ __launch_bounds__(256) void gemm_kernel(const float* __restrict__ A,
                                                   const float* __restrict__ W,
                                                   const float* __restrict__ bias,
                                                   float* __restrict__ C, int M) {
  constexpr int TN = NCOL / 16;  // 8 for 128, 4 for 64
  __shared__ float Wt[NCOL * 128];
  int tid = threadIdx.x;
  int row0 = blockIdx.x * 128;

  // stage W transposed -> Wt[col][k], swizzled: slot k4 ^ ((col>>3)&7)
  constexpr int WI = (128 * (NCOL / 4)) / 256;
#pragma unroll
  for (int i = 0; i < WI; ++i) {
    int idx = tid + i * 256;
    int k = idx / (NCOL / 4);
    int c0 = (idx % (NCOL / 4)) * 4;
    float4 v = *reinterpret_cast<const float4*>(W + k * NCOL + c0);
    int k4 = k >> 2, kk = k & 3;
    Wt[(c0 + 0) * 128 + ((k4 ^ (((c0 + 0) >> 3) & 7)) << 2) + kk] = v.x;
    Wt[(c0 + 1) * 128 + ((k4 ^ (((c0 + 1) >> 3) & 7)) << 2) + kk] = v.y;
    Wt[(c0 + 2) * 128 + ((k4 ^ (((c0 + 2) >> 3) & 7)) << 2) + kk] = v.z;
    Wt[(c0 + 3) * 128 + ((k4 ^ (((c0 + 3) >> 3) & 7)) << 2) + kk] = v.w;
  }

  int tx = tid & 15, ty = tid >> 4;
  int cbase = tx * TN;
  int sw = (cbase >> 3) & 7;  // uniform over this thread's cols

  // 8 row base pointers, clamped for the tail block (stores re-check real index)
  const float* Ar[8];
#pragma unroll
  for (int r = 0; r < 8; ++r) {
    int gr = row0 + ty * 8 + r;
    if (gr > M - 1) gr = M - 1;
    Ar[r] = A + (size_t)gr * 128;
  }

  float acc[8][TN];
#pragma unroll
  for (int r = 0; r < 8; ++r)
#pragma unroll
    for (int c = 0; c < TN; ++c) acc[r][c] = 0.f;

  float4 a0[8], a1[8];
#pragma unroll
  for (int r = 0; r < 8; ++r) a0[r] = *reinterpret_cast<const float4*>(Ar[r] + 0);

  __syncthreads();  // Wt ready

#pragma unroll 1
  for (int k4 = 0; k4 < 32; k4 += 2) {
    // prefetch k4+1 into a1
#pragma unroll
    for (int r = 0; r < 8; ++r)
      a1[r] = *reinterpret_cast<const float4*>(Ar[r] + (k4 + 1) * 4);
    {
      int wo = (k4 ^ sw) << 2;
#pragma unroll
      for (int c = 0; c < TN; ++c) {
        float4 w = *reinterpret_cast<const float4*>(&Wt[(cbase + c) * 128 + wo]);
#pragma unroll
        for (int r = 0; r < 8; ++r) {
          acc[r][c] = fmaf(a0[r].x, w.x, acc[r][c]);
          acc[r][c] = fmaf(a0[r].y, w.y, acc[r][c]);
          acc[r][c] = fmaf(a0[r].z, w.z, acc[r][c]);
          acc[r][c] = fmaf(a0[r].w, w.w, acc[r][c]);
        }
      }
    }
    // prefetch k4+2 into a0 (clamped on last iteration; values unused)
    int kn = k4 + 2 < 31 ? k4 + 2 : 31;
#pragma unroll
    for (int r = 0; r < 8; ++r)
      a0[r] = *reinterpret_cast<const float4*>(Ar[r] + kn * 4);
    {
      int wo = ((k4 + 1) ^ sw) << 2;
#pragma unroll
      for (int c = 0; c < TN; ++c) {
        float4 w = *reinterpret_cast<const float4*>(&Wt[(cbase + c) * 128 + wo]);
#pragma unroll
        for (int r = 0; r < 8; ++r) {
          acc[r][c] = fmaf(a1[r].x, w.x, acc[r][c]);
          acc[r][c] = fmaf(a1[r].y, w.y, acc[r][c]);
          acc[r][c] = fmaf(a1[r].z, w.z, acc[r][c]);
          acc[r][c] = fmaf(a1[r].w, w.w, acc[r][c]);
        }
      }
    }
  }

#pragma unroll
  for (int r = 0; r < 8; ++r) {
    int gr = row0 + ty * 8 + r;
    if (gr < M) {
#pragma unroll
      for (int c = 0; c < TN; c += 4) {
        float4 o;
        float v0 = acc[r][c + 0], v1 = acc[r][c + 1], v2 = acc[r][c + 2], v3 = acc[r][c + 3];
        if (BIAS) {
          v0 += bias[cbase + c + 0]; v1 += bias[cbase + c + 1];
          v2 += bias[cbase + c + 2]; v3 += bias[cbase + c + 3];
        }
        if (RELU) {
          v0 = fmaxf(v0, 0.f); v1 = fmaxf(v1, 0.f);
          v2 = fmaxf(v2, 0.f); v3 = fmaxf(v3, 0.f);
        }
        o.x = v0; o.y = v1; o.z = v2; o.w = v3;
        *reinterpret_cast<float4*>(C + (size_t)gr * NCOL + cbase + c) = o;
      }
    }
  }
}

// ---------------- pull-style aggregation ----------------
// 1 node per wave. Lanes cover features with float4; wave processes 2 (128f)
// or 4 (64f) edges per iteration, cross-slot shfl_xor reduction at the end.

__global__ __launch_bounds__(256) void agg1_kernel(const float* __restrict__ h,
                                                   const int* __restrict__ offs,
                                                   const int* __restrict__ csr,
                                                   const float* __restrict__ dis,
                                                   const float* __restrict__ b,
                                                   float* __restrict__ zout, int n) {
  int wid = threadIdx.x >> 6, lane = threadIdx.x & 63;
  int node = blockIdx.x * 4 + wid;
  if (node >= n) return;
  int half = lane >> 5;
  int fl = (lane & 31) << 2;
  float dn = dis[node];
  float4 acc = make_float4(0.f, 0.f, 0.f, 0.f);
  if (half == 0) {
    float4 hv = *reinterpret_cast<const float4*>(h + (size_t)node * 128 + fl);
    float s2 = dn * dn;
    acc.x = hv.x * s2; acc.y = hv.y * s2; acc.z = hv.z * s2; acc.w = hv.w * s2;
  }
  int jb = offs[node], je = offs[node + 1];
  for (int bs = jb; bs < je; bs += 64) {
    int idx = bs + lane;
    int sl = 0; float wl = 0.f;
    if (idx < je) { sl = csr[idx]; wl = dis[sl] * dn; }
    int m = je - bs; if (m > 64) m = 64;
    for (int t = 0; t < m; t += 4) {
      int e0 = t + half, e1 = t + 2 + half;
      int s0 = __shfl(sl, e0, 64); float w0 = __shfl(wl, e0, 64);
      int s1 = __shfl(sl, e1, 64); float w1 = __shfl(wl, e1, 64);
      float4 v0 = *reinterpret_cast<const float4*>(h + (size_t)s0 * 128 + fl);
      float4 v1 = *reinterpret_cast<const float4*>(h + (size_t)s1 * 128 + fl);
      acc.x = fmaf(v0.x, w0, acc.x); acc.y = fmaf(v0.y, w0, acc.y);
      acc.z = fmaf(v0.z, w0, acc.z); acc.w = fmaf(v0.w, w0, acc.w);
      acc.x = fmaf(v1.x, w1, acc.x); acc.y = fmaf(v1.y, w1, acc.y);
      acc.z = fmaf(v1.z, w1, acc.z); acc.w = fmaf(v1.w, w1, acc.w);
    }
  }
  acc.x += __shfl_xor(acc.x, 32, 64);
  acc.y += __shfl_xor(acc.y, 32, 64);
  acc.z += __shfl_xor(acc.z, 32, 64);
  acc.w += __shfl_xor(acc.w, 32, 64);
  if (lane < 32) {
    float4 bb = *reinterpret_cast<const float4*>(b + fl);
    float4 o;
    o.x = fmaxf(acc.x + bb.x, 0.f);
    o.y = fmaxf(acc.y + bb.y, 0.f);
    o.z = fmaxf(acc.z + bb.z, 0.f);
    o.w = fmaxf(acc.w + bb.w, 0.f);
    *reinterpret_cast<float4*>(zout + (size_t)node * 128 + fl) = o;
  }
}

__global__ __launch_bounds__(256) void agg2_kernel(const float* __restrict__ h,
                                                   const int* __restrict__ offs,
                                                   const int* __restrict__ csr,
                                                   const float* __restrict__ dis,
                                                   const float* __restrict__ b,
                                                   const float* __restrict__ zmlp,
                                                   const float* __restrict__ spi,
                                                   const float* __restrict__ logT,
                                                   float* __restrict__ out, int n) {
  int wid = threadIdx.x >> 6, lane = threadIdx.x & 63;
  int node = blockIdx.x * 4 + wid;
  if (node >= n) return;
  int slot = lane >> 4;
  int fl = (lane & 15) << 2;
  float dn = dis[node];
  float4 acc = make_float4(0.f, 0.f, 0.f, 0.f);
  if (slot == 0) {
    float4 hv = *reinterpret_cast<const float4*>(h + (size_t)node * 64 + fl);
    float s2 = dn * dn;
    acc.x = hv.x * s2; acc.y = hv.y * s2; acc.z = hv.z * s2; acc.w = hv.w * s2;
  }
  int jb = offs[node], je = offs[node + 1];
  for (int bs = jb; bs < je; bs += 64) {
    int idx = bs + lane;
    int sl = 0; float wl = 0.f;
    if (idx < je) { sl = csr[idx]; wl = dis[sl] * dn; }
    int m = je - bs; if (m > 64) m = 64;
    for (int t = 0; t < m; t += 8) {
      int e0 = t + slot, e1 = t + 4 + slot;
      int s0 = __shfl(sl, e0, 64); float w0 = __shfl(wl, e0, 64);
      int s1 = __shfl(sl, e1, 64); float w1 = __shfl(wl, e1, 64);
      float4 v0 = *reinterpret_cast<const float4*>(h + (size_t)s0 * 64 + fl);
      float4 v1 = *reinterpret_cast<const float4*>(h + (size_t)s1 * 64 + fl);
      acc.x = fmaf(v0.x, w0, acc.x); acc.y = fmaf(v0.y, w0, acc.y);
      acc.z = fmaf(v0.z, w0, acc.z); acc.w = fmaf(v0.w, w0, acc.w);
      acc.x = fmaf(v1.x, w1, acc.x); acc.y = fmaf(v1.y, w1, acc.y);
      acc.z = fmaf(v1.z, w1, acc.z); acc.w = fmaf(v1.w, w1, acc.w);
    }
  }
  acc.x += __shfl_xor(acc.x, 16, 64);
  acc.y += __shfl_xor(acc.y, 16, 64);
  acc.z += __shfl_xor(acc.z, 16, 64);
  acc.w += __shfl_xor(acc.w, 16, 64);
  acc.x += __shfl_xor(acc.x, 32, 64);
  acc.y += __shfl_xor(acc.y, 32, 64);
  acc.z += __shfl_xor(acc.z, 32, 64);
  acc.w += __shfl_xor(acc.w, 32, 64);
  if (lane < 16) {
    float beta = 1.f / (1.f + expf(-((spi[0] - 0.67f) / expf(logT[0]))));
    float4 bb = *reinterpret_cast<const float4*>(b + fl);
    float4 mv = *reinterpret_cast<const float4*>(zmlp + (size_t)node * 64 + fl);
    float4 o;
    o.x = beta * (acc.x + bb.x) + (1.f - beta) * mv.x;
    o.y = beta * (acc.y + bb.y) + (1.f - beta) * mv.y;
    o.z = beta * (acc.z + bb.z) + (1.f - beta) * mv.z;
    o.w = beta * (acc.w + bb.w) + (1.f - beta) * mv.w;
    *reinterpret_cast<float4*>(out + (size_t)node * 64 + fl) = o;
  }
}

// ---------------- launcher ----------------

extern "C" void kernel_launch(void* const* d_in, const int* in_sizes, int n_in,
                              void* d_out, int out_size, void* d_ws, size_t ws_size,
                              hipStream_t stream) {
  const float* x    = (const float*)d_in[0];
  const int*   ei   = (const int*)d_in[1];
  const float* spi  = (const float*)d_in[2];
  const float* Wg1  = (const float*)d_in[3];
  const float* bg1  = (const float*)d_in[4];
  const float* Wg2  = (const float*)d_in[5];
  const float* bg2  = (const float*)d_in[6];
  const float* Wm1  = (const float*)d_in[7];
  const float* bm1  = (const float*)d_in[8];
  const float* Wm2  = (const float*)d_in[9];
  const float* bm2  = (const float*)d_in[10];
  const float* logT = (const float*)d_in[11];
  float* out = (float*)d_out;

  int n = in_sizes[0] / 128;   // 100000
  int E = in_sizes[1] / 2;     // 1600000
  int nb = (n + 1023) / 1024;

  char* p = (char*)d_ws;
  auto alloc = [&](size_t bytes) -> char* {
    char* r = p;
    p += (bytes + 255) & ~(size_t)255;
    return r;
  };
  int*   cnt    = (int*)alloc((size_t)n * 4);
  int*   offs   = (int*)alloc((size_t)(n + 1) * 4);
  float* dis    = (float*)alloc((size_t)n * 4);
  int*   bsums  = (int*)alloc((size_t)nb * 4);
  int*   rank   = (int*)alloc((size_t)E * 4);
  int*   csr    = (int*)alloc((size_t)E * 4);
  float* h1     = (float*)alloc((size_t)n * 128 * 4);  // reused as h2
  float* hm     = (float*)alloc((size_t)n * 128 * 4);
  float* z      = (float*)alloc((size_t)n * 128 * 4);  // reused as z_mlp

  hipMemsetAsync(cnt, 0, (size_t)n * 4, stream);

  int eb = (E + 255) / 256;
  rank_kernel<<<eb, 256, 0, stream>>>(ei, cnt, rank, E);
  scan_block_kernel<<<nb, 256, 0, stream>>>(cnt, offs, bsums, dis, n);
  scan_tops_kernel<<<1, 64, 0, stream>>>(bsums, nb, offs, n);
  scan_add_kernel<<<(n + 255) / 256, 256, 0, stream>>>(bsums, offs, n);
  scatter_kernel<<<eb, 256, 0, stream>>>(ei, rank, offs, csr, E);

  int gb = (n + 127) / 128;
  gemm_kernel<128, false, false><<<gb, 256, 0, stream>>>(x, Wg1, nullptr, h1, n);
  gemm_kernel<128, true,  true ><<<gb, 256, 0, stream>>>(x, Wm1, bm1, hm, n);
  agg1_kernel<<<(n + 3) / 4, 256, 0, stream>>>(h1, offs, csr, dis, bg1, z, n);

  float* h2   = h1;  // h1 dead after agg1
  gemm_kernel<64, false, false><<<gb, 256, 0, stream>>>(z, Wg2, nullptr, h2, n);
  float* zmlp = z;   // z dead after the gemm above (stream-ordered)
  gemm_kernel<64, false, true ><<<gb, 256, 0, stream>>>(hm, Wm2, bm2, zmlp, n);

  agg2_kernel<<<(n + 3) / 4, 256, 0, stream>>>(h2, offs, csr, dis, bg2, zmlp, spi, logT, out, n);
}

// Round 8
// 587.279 us; speedup vs baseline: 1.3646x; 1.0350x over previous
//
#include <hip/hip_runtime.h>
#include <math.h>

// ---------------- graph build pieces ----------------

__global__ void scan_block_kernel(const int* __restrict__ cnt, int* __restrict__ part,
                                  int* __restrict__ bsums, float* __restrict__ dis, int n) {
  __shared__ int wsum[4];
  int tid = threadIdx.x;
  int lane = tid & 63, wid = tid >> 6;
  int base = blockIdx.x * 1024 + tid * 4;
  int v0 = 0, v1 = 0, v2 = 0, v3 = 0;
  if (base + 0 < n) { v0 = cnt[base + 0]; dis[base + 0] = 1.f / sqrtf((float)(v0 + 1)); }
  if (base + 1 < n) { v1 = cnt[base + 1]; dis[base + 1] = 1.f / sqrtf((float)(v1 + 1)); }
  if (base + 2 < n) { v2 = cnt[base + 2]; dis[base + 2] = 1.f / sqrtf((float)(v2 + 1)); }
  if (base + 3 < n) { v3 = cnt[base + 3]; dis[base + 3] = 1.f / sqrtf((float)(v3 + 1)); }
  int tot = v0 + v1 + v2 + v3;
  int x = tot;
#pragma unroll
  for (int d = 1; d < 64; d <<= 1) { int y = __shfl_up(x, d, 64); if (lane >= d) x += y; }
  if (lane == 63) wsum[wid] = x;
  __syncthreads();
  int wpre = 0;
#pragma unroll
  for (int w = 0; w < 4; ++w) wpre += (w < wid) ? wsum[w] : 0;
  int ex = wpre + x - tot;
  if (base + 0 < n) part[base + 0] = ex; ex += v0;
  if (base + 1 < n) part[base + 1] = ex; ex += v1;
  if (base + 2 < n) part[base + 2] = ex; ex += v2;
  if (base + 3 < n) part[base + 3] = ex;
  if (tid == 255) bsums[blockIdx.x] = wpre + x;
}

__global__ void scan_tops_kernel(int* __restrict__ bsums, int nb, int* __restrict__ offs, int n) {
  int lane = threadIdx.x;  // launched with 64
  int run = 0;
  for (int base = 0; base < nb; base += 64) {
    int i = base + lane;
    int v = (i < nb) ? bsums[i] : 0;
    int x = v;
#pragma unroll
    for (int d = 1; d < 64; d <<= 1) { int y = __shfl_up(x, d, 64); if (lane >= d) x += y; }
    if (i < nb) bsums[i] = run + x - v;  // exclusive prefix
    run += __shfl(x, 63, 64);
  }
  if (lane == 0) offs[n] = run;
}

__global__ void scan_add_kernel(const int* __restrict__ bsums, int* __restrict__ offs, int n) {
  int i = blockIdx.x * 256 + threadIdx.x;
  if (i < n) offs[i] += bsums[i >> 10];
}

// place src into CSR slot — no atomics.
__global__ void scatter_kernel(const int* __restrict__ ei, const int* __restrict__ rank,
                               const int* __restrict__ offs, int* __restrict__ csr, int E) {
  int e = blockIdx.x * 256 + threadIdx.x;
  if (e < E) {
    int s = ei[e];
    int d = ei[E + e];
    csr[offs[d] + rank[e]] = s;
  }
}

// ---------------- fp32 GEMM tile as device function ----------------
// 256 threads, 128-row x NCOL tile, 8 x TN micro-tile. Only Wt (transposed,
// XOR-swizzled) in LDS. A read from global (16-lane broadcast), register
// ping-pong prefetch, no barrier in the k-loop.

template <int NCOL, bool RELU, bool BIAS>
__device__ void gemm_tile(const float* __restrict__ A, const float* __restrict__ W,
                          const float* __restrict__ bias, float* __restrict__ C,
                          int M, int block, float* Wt) {
  constexpr int TN = NCOL / 16;  // 8 for 128, 4 for 64
  int tid = threadIdx.x;
  int row0 = block * 128;

  constexpr int WI = (128 * (NCOL / 4)) / 256;
#pragma unroll
  for (int i = 0; i < WI; ++i) {
    int idx = tid + i * 256;
    int k = idx / (NCOL / 4);
    int c0 = (idx % (NCOL / 4)) * 4;
    float4 v = *reinterpret_cast<const float4*>(W + k * NCOL + c0);
    int k4 = k >> 2, kk = k & 3;
    Wt[(c0 + 0) * 128 + ((k4 ^ (((c0 + 0) >> 3) & 7)) << 2) + kk] = v.x;
    Wt[(c0 + 1) * 128 + ((k4 ^ (((c0 + 1) >> 3) & 7)) << 2) + kk] = v.y;
    Wt[(c0 + 2) * 128 + ((k4 ^ (((c0 + 2) >> 3) & 7)) << 2) + kk] = v.z;
    Wt[(c0 + 3) * 128 + ((k4 ^ (((c0 + 3) >> 3) & 7)) << 2) + kk] = v.w;
  }

  int tx = tid & 15, ty = tid >> 4;
  int cbase = tx * TN;
  int sw = (cbase >> 3) & 7;

  const float* Ar[8];
#pragma unroll
  for (int r = 0; r < 8; ++r) {
    int gr = row0 + ty * 8 + r;
    if (gr > M - 1) gr = M - 1;
    Ar[r] = A + (size_t)gr * 128;
  }

  float acc[8][TN];
#pragma unroll
  for (int r = 0; r < 8; ++r)
#pragma unroll
    for (int c = 0; c < TN; ++c) acc[r][c] = 0.f;

  float4 a0[8], a1[8];
#pragma unroll
  for (int r = 0; r < 8; ++r) a0[r] = *reinterpret_cast<const float4*>(Ar[r] + 0);

  __syncthreads();  // Wt ready

#pragma unroll 1
  for (int k4 = 0; k4 < 32; k4 += 2) {
#pragma unroll
    for (int r = 0; r < 8; ++r)
      a1[r] = *reinterpret_cast<const float4*>(Ar[r] + (k4 + 1) * 4);
    {
      int wo = (k4 ^ sw) << 2;
#pragma unroll
      for (int c = 0; c < TN; ++c) {
        float4 w = *reinterpret_cast<const float4*>(&Wt[(cbase + c) * 128 + wo]);
#pragma unroll
        for (int r = 0; r < 8; ++r) {
          acc[r][c] = fmaf(a0[r].x, w.x, acc[r][c]);
          acc[r][c] = fmaf(a0[r].y, w.y, acc[r][c]);
          acc[r][c] = fmaf(a0[r].z, w.z, acc[r][c]);
          acc[r][c] = fmaf(a0[r].w, w.w, acc[r][c]);
        }
      }
    }
    int kn = k4 + 2 < 31 ? k4 + 2 : 31;
#pragma unroll
    for (int r = 0; r < 8; ++r)
      a0[r] = *reinterpret_cast<const float4*>(Ar[r] + kn * 4);
    {
      int wo = ((k4 + 1) ^ sw) << 2;
#pragma unroll
      for (int c = 0; c < TN; ++c) {
        float4 w = *reinterpret_cast<const float4*>(&Wt[(cbase + c) * 128 + wo]);
#pragma unroll
        for (int r = 0; r < 8; ++r) {
          acc[r][c] = fmaf(a1[r].x, w.x, acc[r][c]);
          acc[r][c] = fmaf(a1[r].y, w.y, acc[r][c]);
          acc[r][c] = fmaf(a1[r].z, w.z, acc[r][c]);
          acc[r][c] = fmaf(a1[r].w, w.w, acc[r][c]);
        }
      }
    }
  }

#pragma unroll
  for (int r = 0; r < 8; ++r) {
    int gr = row0 + ty * 8 + r;
    if (gr < M) {
#pragma unroll
      for (int c = 0; c < TN; c += 4) {
        float4 o;
        float v0 = acc[r][c + 0], v1 = acc[r][c + 1], v2 = acc[r][c + 2], v3 = acc[r][c + 3];
        if (BIAS) {
          v0 += bias[cbase + c + 0]; v1 += bias[cbase + c + 1];
          v2 += bias[cbase + c + 2]; v3 += bias[cbase + c + 3];
        }
        if (RELU) {
          v0 = fmaxf(v0, 0.f); v1 = fmaxf(v1, 0.f);
          v2 = fmaxf(v2, 0.f); v3 = fmaxf(v3, 0.f);
        }
        o.x = v0; o.y = v1; o.z = v2; o.w = v3;
        *reinterpret_cast<float4*>(C + (size_t)gr * NCOL + cbase + c) = o;
      }
    }
  }
}

// ---------------- K1: fused rank (atomic) + gemm1 + gemmMLP1 ----------------
// Bresenham-interleaved block types so atomic-latency-bound rank blocks
// co-reside with FMA-bound GEMM blocks on every CU.

__global__ __launch_bounds__(256) void k1_fused(const int* __restrict__ ei, int* __restrict__ cnt,
                                                int* __restrict__ rank, int E,
                                                const float* __restrict__ x,
                                                const float* __restrict__ Wg1, float* __restrict__ h1,
                                                const float* __restrict__ Wm1,
                                                const float* __restrict__ bm1, float* __restrict__ hm,
                                                int M, int nG) {
  __shared__ float Wt[128 * 128];
  int b = blockIdx.x;
  int NB = gridDim.x;
  int g0 = (int)(((long)b * nG) / NB);
  int g1 = (int)(((long)(b + 1) * nG) / NB);
  if (g1 > g0) {
    if (g0 < nG / 2) gemm_tile<128, false, false>(x, Wg1, nullptr, h1, M, g0, Wt);
    else             gemm_tile<128, true,  true >(x, Wm1, bm1,    hm, M, g0 - nG / 2, Wt);
  } else {
    int r = b - g0;
    int e = r * 256 + threadIdx.x;
    if (e < E) rank[e] = atomicAdd(&cnt[ei[E + e]], 1);
  }
}

// ---------------- K8: fused gemm2 + gemmMLP2 (both NCOL=64) ----------------

__global__ __launch_bounds__(256) void k8_fused(const float* __restrict__ z,
                                                const float* __restrict__ Wg2, float* __restrict__ h2,
                                                const float* __restrict__ hm,
                                                const float* __restrict__ Wm2,
                                                const float* __restrict__ bm2, float* __restrict__ zmlp,
                                                int M) {
  __shared__ float Wt[64 * 128];
  int b = blockIdx.x;
  if ((b & 1) == 0) gemm_tile<64, false, false>(z,  Wg2, nullptr, h2,   M, b >> 1, Wt);
  else              gemm_tile<64, false, true >(hm, Wm2, bm2,    zmlp, M, b >> 1, Wt);
}

// ---------------- pull-style aggregation, 4 outstanding gathers/lane ----------------

__global__ __launch_bounds__(256) void agg1_kernel(const float* __restrict__ h,
                                                   const int* __restrict__ offs,
                                                   const int* __restrict__ csr,
                                                   const float* __restrict__ dis,
                                                   const float* __restrict__ b,
                                                   float* __restrict__ zout, int n) {
  int wid = threadIdx.x >> 6, lane = threadIdx.x & 63;
  int node = blockIdx.x * 4 + wid;
  if (node >= n) return;
  int half = lane >> 5;
  int fl = (lane & 31) << 2;
  float dn = dis[node];
  float4 acc = make_float4(0.f, 0.f, 0.f, 0.f);
  float4 acc2 = make_float4(0.f, 0.f, 0.f, 0.f);
  if (half == 0) {
    float4 hv = *reinterpret_cast<const float4*>(h + (size_t)node * 128 + fl);
    float s2 = dn * dn;
    acc.x = hv.x * s2; acc.y = hv.y * s2; acc.z = hv.z * s2; acc.w = hv.w * s2;
  }
  int jb = offs[node], je = offs[node + 1];
  for (int bs = jb; bs < je; bs += 64) {
    int idx = bs + lane;
    int sl = 0; float wl = 0.f;
    if (idx < je) { sl = csr[idx]; wl = dis[sl] * dn; }
    int m = je - bs; if (m > 64) m = 64;
    for (int t = 0; t < m; t += 8) {
      // 8 edges per iteration, 4 outstanding gathers per lane
      int s0 = __shfl(sl, t + half,     64); float w0 = __shfl(wl, t + half,     64);
      int s1 = __shfl(sl, t + 2 + half, 64); float w1 = __shfl(wl, t + 2 + half, 64);
      int s2 = __shfl(sl, t + 4 + half, 64); float w2 = __shfl(wl, t + 4 + half, 64);
      int s3 = __shfl(sl, t + 6 + half, 64); float w3 = __shfl(wl, t + 6 + half, 64);
      float4 v0 = *reinterpret_cast<const float4*>(h + (size_t)s0 * 128 + fl);
      float4 v1 = *reinterpret_cast<const float4*>(h + (size_t)s1 * 128 + fl);
      float4 v2 = *reinterpret_cast<const float4*>(h + (size_t)s2 * 128 + fl);
      float4 v3 = *reinterpret_cast<const float4*>(h + (size_t)s3 * 128 + fl);
      acc.x  = fmaf(v0.x, w0, acc.x);  acc.y  = fmaf(v0.y, w0, acc.y);
      acc.z  = fmaf(v0.z, w0, acc.z);  acc.w  = fmaf(v0.w, w0, acc.w);
      acc.x  = fmaf(v1.x, w1, acc.x);  acc.y  = fmaf(v1.y, w1, acc.y);
      acc.z  = fmaf(v1.z, w1, acc.z);  acc.w  = fmaf(v1.w, w1, acc.w);
      acc2.x = fmaf(v2.x, w2, acc2.x); acc2.y = fmaf(v2.y, w2, acc2.y);
      acc2.z = fmaf(v2.z, w2, acc2.z); acc2.w = fmaf(v2.w, w2, acc2.w);
      acc2.x = fmaf(v3.x, w3, acc2.x); acc2.y = fmaf(v3.y, w3, acc2.y);
      acc2.z = fmaf(v3.z, w3, acc2.z); acc2.w = fmaf(v3.w, w3, acc2.w);
    }
  }
  acc.x += acc2.x; acc.y += acc2.y; acc.z += acc2.z; acc.w += acc2.w;
  acc.x += __shfl_xor(acc.x, 32, 64);
  acc.y += __shfl_xor(acc.y, 32, 64);
  acc.z += __shfl_xor(acc.z, 32, 64);
  acc.w += __shfl_xor(acc.w, 32, 64);
  if (lane < 32) {
    float4 bb = *reinterpret_cast<const float4*>(b + fl);
    float4 o;
    o.x = fmaxf(acc.x + bb.x, 0.f);
    o.y = fmaxf(acc.y + bb.y, 0.f);
    o.z = fmaxf(acc.z + bb.z, 0.f);
    o.w = fmaxf(acc.w + bb.w, 0.f);
    *reinterpret_cast<float4*>(zout + (size_t)node * 128 + fl) = o;
  }
}

__global__ __launch_bounds__(256) void agg2_kernel(const float* __restrict__ h,
                                                   const int* __restrict__ offs,
                                                   const int* __restrict__ csr,
                                                   const float* __restrict__ dis,
                                                   const float* __restrict__ b,
                                                   const float* __restrict__ zmlp,
                                                   const float* __restrict__ spi,
                                                   const float* __restrict__ logT,
                                                   float* __restrict__ out, int n) {
  int wid = threadIdx.x >> 6, lane = threadIdx.x & 63;
  int node = blockIdx.x * 4 + wid;
  if (node >= n) return;
  int slot = lane >> 4;
  int fl = (lane & 15) << 2;
  float dn = dis[node];
  float4 acc = make_float4(0.f, 0.f, 0.f, 0.f);
  float4 acc2 = make_float4(0.f, 0.f, 0.f, 0.f);
  if (slot == 0) {
    float4 hv = *reinterpret_cast<const float4*>(h + (size_t)node * 64 + fl);
    float s2 = dn * dn;
    acc.x = hv.x * s2; acc.y = hv.y * s2; acc.z = hv.z * s2; acc.w = hv.w * s2;
  }
  int jb = offs[node], je = offs[node + 1];
  for (int bs = jb; bs < je; bs += 64) {
    int idx = bs + lane;
    int sl = 0; float wl = 0.f;
    if (idx < je) { sl = csr[idx]; wl = dis[sl] * dn; }
    int m = je - bs; if (m > 64) m = 64;
    for (int t = 0; t < m; t += 16) {
      // 16 edges per iteration, 4 outstanding gathers per lane
      int s0 = __shfl(sl, t + slot,      64); float w0 = __shfl(wl, t + slot,      64);
      int s1 = __shfl(sl, t + 4 + slot,  64); float w1 = __shfl(wl, t + 4 + slot,  64);
      int s2 = __shfl(sl, t + 8 + slot,  64); float w2 = __shfl(wl, t + 8 + slot,  64);
      int s3 = __shfl(sl, t + 12 + slot, 64); float w3 = __shfl(wl, t + 12 + slot, 64);
      float4 v0 = *reinterpret_cast<const float4*>(h + (size_t)s0 * 64 + fl);
      float4 v1 = *reinterpret_cast<const float4*>(h + (size_t)s1 * 64 + fl);
      float4 v2 = *reinterpret_cast<const float4*>(h + (size_t)s2 * 64 + fl);
      float4 v3 = *reinterpret_cast<const float4*>(h + (size_t)s3 * 64 + fl);
      acc.x  = fmaf(v0.x, w0, acc.x);  acc.y  = fmaf(v0.y, w0, acc.y);
      acc.z  = fmaf(v0.z, w0, acc.z);  acc.w  = fmaf(v0.w, w0, acc.w);
      acc.x  = fmaf(v1.x, w1, acc.x);  acc.y  = fmaf(v1.y, w1, acc.y);
      acc.z  = fmaf(v1.z, w1, acc.z);  acc.w  = fmaf(v1.w, w1, acc.w);
      acc2.x = fmaf(v2.x, w2, acc2.x); acc2.y = fmaf(v2.y, w2, acc2.y);
      acc2.z = fmaf(v2.z, w2, acc2.z); acc2.w = fmaf(v2.w, w2, acc2.w);
      acc2.x = fmaf(v3.x, w3, acc2.x); acc2.y = fmaf(v3.y, w3, acc2.y);
      acc2.z = fmaf(v3.z, w3, acc2.z); acc2.w = fmaf(v3.w, w3, acc2.w);
    }
  }
  acc.x += acc2.x; acc.y += acc2.y; acc.z += acc2.z; acc.w += acc2.w;
  acc.x += __shfl_xor(acc.x, 16, 64);
  acc.y += __shfl_xor(acc.y, 16, 64);
  acc.z += __shfl_xor(acc.z, 16, 64);
  acc.w += __shfl_xor(acc.w, 16, 64);
  acc.x += __shfl_xor(acc.x, 32, 64);
  acc.y += __shfl_xor(acc.y, 32, 64);
  acc.z += __shfl_xor(acc.z, 32, 64);
  acc.w += __shfl_xor(acc.w, 32, 64);
  if (lane < 16) {
    float beta = 1.f / (1.f + expf(-((spi[0] - 0.67f) / expf(logT[0]))));
    float4 bb = *reinterpret_cast<const float4*>(b + fl);
    float4 mv = *reinterpret_cast<const float4*>(zmlp + (size_t)node * 64 + fl);
    float4 o;
    o.x = beta * (acc.x + bb.x) + (1.f - beta) * mv.x;
    o.y = beta * (acc.y + bb.y) + (1.f - beta) * mv.y;
    o.z = beta * (acc.z + bb.z) + (1.f - beta) * mv.z;
    o.w = beta * (acc.w + bb.w) + (1.f - beta) * mv.w;
    *reinterpret_cast<float4*>(out + (size_t)node * 64 + fl) = o;
  }
}

// ---------------- launcher ----------------

extern "C" void kernel_launch(void* const* d_in, const int* in_sizes, int n_in,
                              void* d_out, int out_size, void* d_ws, size_t ws_size,
                              hipStream_t stream) {
  const float* x    = (const float*)d_in[0];
  const int*   ei   = (const int*)d_in[1];
  const float* spi  = (const float*)d_in[2];
  const float* Wg1  = (const float*)d_in[3];
  const float* bg1  = (const float*)d_in[4];
  const float* Wg2  = (const float*)d_in[5];
  const float* bg2  = (const float*)d_in[6];
  const float* Wm1  = (const float*)d_in[7];
  const float* bm1  = (const float*)d_in[8];
  const float* Wm2  = (const float*)d_in[9];
  const float* bm2  = (const float*)d_in[10];
  const float* logT = (const float*)d_in[11];
  float* out = (float*)d_out;

  int n = in_sizes[0] / 128;   // 100000
  int E = in_sizes[1] / 2;     // 1600000
  int nb = (n + 1023) / 1024;

  char* p = (char*)d_ws;
  auto alloc = [&](size_t bytes) -> char* {
    char* r = p;
    p += (bytes + 255) & ~(size_t)255;
    return r;
  };
  int*   cnt    = (int*)alloc((size_t)n * 4);
  int*   offs   = (int*)alloc((size_t)(n + 1) * 4);
  float* dis    = (float*)alloc((size_t)n * 4);
  int*   bsums  = (int*)alloc((size_t)nb * 4);
  // rank (E*4 = 6.4MB) and zmlp (n*64*4 = 25.6MB) have disjoint lifetimes:
  // rank: written K1, read scatter. zmlp: written K8, read agg2.
  char*  ru     = alloc((size_t)n * 64 * 4);
  int*   rank   = (int*)ru;
  float* zmlp   = (float*)ru;
  int*   csr    = (int*)alloc((size_t)E * 4);
  float* h1     = (float*)alloc((size_t)n * 128 * 4);  // reused as h2
  float* hm     = (float*)alloc((size_t)n * 128 * 4);
  float* z      = (float*)alloc((size_t)n * 128 * 4);

  hipMemsetAsync(cnt, 0, (size_t)n * 4, stream);

  int eb = (E + 255) / 256;        // 6250
  int gb = (n + 127) / 128;        // 782
  int nG = 2 * gb;                 // 1564 gemm blocks in K1

  // K1: rank atomics + both 128-col GEMMs, interleaved
  k1_fused<<<eb + nG, 256, 0, stream>>>(ei, cnt, rank, E, x, Wg1, h1, Wm1, bm1, hm, n, nG);

  scan_block_kernel<<<nb, 256, 0, stream>>>(cnt, offs, bsums, dis, n);
  scan_tops_kernel<<<1, 64, 0, stream>>>(bsums, nb, offs, n);
  scan_add_kernel<<<(n + 255) / 256, 256, 0, stream>>>(bsums, offs, n);
  scatter_kernel<<<eb, 256, 0, stream>>>(ei, rank, offs, csr, E);

  agg1_kernel<<<(n + 3) / 4, 256, 0, stream>>>(h1, offs, csr, dis, bg1, z, n);

  float* h2 = h1;  // h1 dead after agg1
  // K8: gemm2 (z@Wg2 -> h2) + gemmMLP2 (hm@Wm2+bm2 -> zmlp), interleaved
  k8_fused<<<2 * gb, 256, 0, stream>>>(z, Wg2, h2, hm, Wm2, bm2, zmlp, n);

  agg2_kernel<<<(n + 3) / 4, 256, 0, stream>>>(h2, offs, csr, dis, bg2, zmlp, spi, logT, out, n);
}